// Round 2
// baseline (248.107 us; speedup 1.0000x reference)
//
#include <hip/hip_runtime.h>
#include <hip/hip_bf16.h>

// StyleLoss — x (1,512,64,64) fp32, target (512,256,256) fp32 -> scalar loss.
// loss = mean_{i,a,b}( (g_full[(i+a)%512,(i+b)%512]/2^20 - target[i,a,b])^2 ) * 1e6
// g_full = feats @ feats^T, feats = x reshaped (512, 4096), bf16 MFMA (tol ~2%).
//
// R5: timed iter = 2x ~78.5us ws-poison fills (harness) + ~52us ours.
//  (a) finish fused into loss via last-block ticket (512 blocks, agent-scope
//      atomics; counter zeroed by reduce each iter). 5 -> 4 kernels.
//  (b) gemm SPLITK 4->8: 512 blocks = 2 blocks/CU so barrier drains overlap
//      across blocks (was 1 wave/SIMD = zero hiding).
//
// ws: [0,4MB) bf16 feats; [4,12MB) fp32 g_part[8][512*512];
//     [12MB,+1.5MB) fp32 g_pad[512][768]; fp32 partials[512]; uint counter.

typedef __attribute__((ext_vector_type(8))) short bf16x8;   // 8 bf16 in 4 VGPRs
typedef __attribute__((ext_vector_type(4))) float f32x4;

#define CH 512
#define KDIM 4096
#define FEATS_ELEMS (CH * KDIM)
#define SPLITK 8
#define LOSS_BLOCKS 512
#define GPAD 768

// ---------------------------------------------------------------- convert ----
__global__ __launch_bounds__(256) void convert_kernel(const float* __restrict__ x,
                                                      __hip_bfloat16* __restrict__ feats) {
    int idx = blockIdx.x * 256 + threadIdx.x;   // 262144 threads, 8 elems each
    const float4* x4 = (const float4*)x;
    float4 v0 = x4[idx * 2 + 0];
    float4 v1 = x4[idx * 2 + 1];
    float f[8] = {v0.x, v0.y, v0.z, v0.w, v1.x, v1.y, v1.z, v1.w};
    union { ushort u[8]; uint4 v; } o;
#pragma unroll
    for (int i = 0; i < 8; ++i) {
        __hip_bfloat16 b = __float2bfloat16(f[i]);
        o.u[i] = *reinterpret_cast<ushort*>(&b);
    }
    *reinterpret_cast<uint4*>(feats + idx * 8) = o.v;
}

// ---------------------------------------------------------------- gemm -------
// C = F * F^T, F 512x4096 bf16 row-major. 64x64 tile, BK=64, split-K=8
// (512 blocks = 2/CU), register prefetch, plain stores into slice g_part[kz].
#define BM 64
#define BK 64
#define LDT 72   // padded LDS stride in bf16: 144 B (b128-aligned, 2-way alias = free)

__global__ __launch_bounds__(256) void gemm_kernel(const __hip_bfloat16* __restrict__ feats,
                                                   float* __restrict__ g_part) {
    __shared__ __hip_bfloat16 a_tile[BM * LDT];
    __shared__ __hip_bfloat16 b_tile[BM * LDT];

    const int bm = blockIdx.x, bn = blockIdx.y, kz = blockIdx.z;
    const int tid  = threadIdx.x;
    const int lane = tid & 63;
    const int w    = tid >> 6;        // wave 0..3 -> M rows w*16..w*16+15
    const int m    = lane & 15;
    const int q    = lane >> 4;       // quad: k offset q*8

    const int srow = tid >> 3;        // staging row 0..31 (+32 for p=1)
    const int scol = (tid & 7) * 8;   // 0..56 step 8

    f32x4 acc[4] = {};                // 4 N-subtiles of 16 cols

    const int NT = (KDIM / SPLITK) / BK;            // 8 k-tiles per block
    const int k0base = kz * (KDIM / SPLITK);        // 512 per split

    const __hip_bfloat16* arow0 = feats + (size_t)(bm * 64 + srow) * KDIM + k0base + scol;
    const __hip_bfloat16* brow0 = feats + (size_t)(bn * 64 + srow) * KDIM + k0base + scol;

    uint4 pa[2], pb[2];
#pragma unroll
    for (int p = 0; p < 2; ++p) {
        pa[p] = *(const uint4*)(arow0 + (size_t)p * 32 * KDIM);
        pb[p] = *(const uint4*)(brow0 + (size_t)p * 32 * KDIM);
    }

    for (int kt = 0; kt < NT; ++kt) {
        if (kt > 0) __syncthreads();               // previous MFMA reads done
#pragma unroll
        for (int p = 0; p < 2; ++p) {
            uint* ap = (uint*)(a_tile + (srow + p * 32) * LDT + scol);
            ap[0] = pa[p].x; ap[1] = pa[p].y; ap[2] = pa[p].z; ap[3] = pa[p].w;
            uint* bp = (uint*)(b_tile + (srow + p * 32) * LDT + scol);
            bp[0] = pb[p].x; bp[1] = pb[p].y; bp[2] = pb[p].z; bp[3] = pb[p].w;
        }
        __syncthreads();
        if (kt + 1 < NT) {                         // prefetch next tile (overlaps MFMA)
            const int ko = (kt + 1) * BK;
#pragma unroll
            for (int p = 0; p < 2; ++p) {
                pa[p] = *(const uint4*)(arow0 + (size_t)p * 32 * KDIM + ko);
                pb[p] = *(const uint4*)(brow0 + (size_t)p * 32 * KDIM + ko);
            }
        }
#pragma unroll
        for (int ks = 0; ks < 2; ++ks) {
            const int kk = ks * 32 + q * 8;
            bf16x8 afrag = *(const bf16x8*)(a_tile + (w * 16 + m) * LDT + kk);
#pragma unroll
            for (int j = 0; j < 4; ++j) {
                bf16x8 bfrag = *(const bf16x8*)(b_tile + (j * 16 + m) * LDT + kk);
                acc[j] = __builtin_amdgcn_mfma_f32_16x16x32_bf16(afrag, bfrag, acc[j], 0, 0, 0);
            }
        }
    }

    // Epilogue: C/D layout col = lane&15, row = (lane>>4)*4 + reg (verified m89/m91)
    float* gp = g_part + ((size_t)kz << 18);
    const int col = lane & 15;
    const int rq  = (lane >> 4) * 4;
#pragma unroll
    for (int j = 0; j < 4; ++j) {
#pragma unroll
        for (int reg = 0; reg < 4; ++reg) {
            const int rg = bm * 64 + w * 16 + rq + reg;
            const int cg = bn * 64 + j * 16 + col;
            gp[rg * CH + cg] = acc[j][reg];
        }
    }
}

// ---------------------------------------------------------------- reduce -----
// g_pad[row][0..767] = gscale * sum of 8 split-K slices; cols 512..767 duplicate
// cols 0..255 so the loss kernel reads (i+b)%512 as ONE contiguous float4.
// Also zeroes the loss ticket counter (stream order => visible to loss).
__global__ __launch_bounds__(256) void reduce_pad_kernel(const float* __restrict__ g_part,
                                                         float* __restrict__ g_pad,
                                                         unsigned int* __restrict__ counter) {
    if (blockIdx.x == 0 && threadIdx.x == 0) *counter = 0u;
    const float gscale = 1.0f / 1048576.0f;          // 1/(b*local_ch*w*h)
    int t = blockIdx.x * 256 + threadIdx.x;          // 0..65535
    const float4* p = (const float4*)g_part;
    float4 s = p[t];
#pragma unroll
    for (int sl = 1; sl < SPLITK; ++sl) {
        float4 v = p[t + sl * 65536];
        s.x += v.x; s.y += v.y; s.z += v.z; s.w += v.w;
    }
    s.x *= gscale; s.y *= gscale; s.z *= gscale; s.w *= gscale;
    const int row = t >> 7;                          // 128 float4 per row
    const int c4  = t & 127;
    float4* dst = (float4*)(g_pad + (size_t)row * GPAD);
    dst[c4] = s;
    if (c4 < 64) dst[c4 + 128] = s;                  // duplicate cols 0..255
}

// ---------------------------------------------------------------- loss -------
// 512 blocks, one full i per block (64 float4 of target per thread).
// g-read is ONE 16B load per step: g_pad[row*768 + i + 4*lane .. +3].
// Last-block ticket fuses the finish: agent-scope atomics cross XCD L2s.
__global__ __launch_bounds__(256) void loss_kernel(const float* __restrict__ target,
                                                   const float* __restrict__ g_pad,
                                                   float* __restrict__ partials,
                                                   unsigned int* __restrict__ counter,
                                                   float* __restrict__ out) {
    const float lscale = 1.0e6f / 33554432.0f;       // WEIGHT / count

    const int tid  = threadIdx.x;
    const int lane = tid & 63;
    const int wv   = tid >> 6;
    const int i    = blockIdx.x;                     // 0..511

    const float4* t4 = (const float4*)target;
    const float* gbase = g_pad + i + 4 * lane;       // column start, per thread
    float acc = 0.0f;

    for (int oj = 0; oj < 16; ++oj) {                // ob = oj>>2, j = oj&3
        const int ob = oj >> 2, j = oj & 3;
        float4 tv[4];
        float4 gv[4];
#pragma unroll
        for (int k = 0; k < 4; ++k) {
            const int idx4 = i * 16384 + ob * 4096 + j * 1024 + k * 256 + tid;
            tv[k] = t4[idx4];
            const int row = (i + ob * 64 + j * 16 + k * 4 + wv) & 511;
            __builtin_memcpy(&gv[k], gbase + (size_t)row * GPAD, sizeof(float4));
        }
#pragma unroll
        for (int k = 0; k < 4; ++k) {
            float d0 = gv[k].x - tv[k].x;
            float d1 = gv[k].y - tv[k].y;
            float d2 = gv[k].z - tv[k].z;
            float d3 = gv[k].w - tv[k].w;
            acc += d0 * d0 + d1 * d1 + d2 * d2 + d3 * d3;
        }
    }

    // wave reduce, cross-wave via LDS, one agent-scope partial store per block
#pragma unroll
    for (int off = 32; off > 0; off >>= 1) acc += __shfl_xor(acc, off, 64);
    __shared__ float wsum[4];
    __shared__ unsigned int ticket_s;
    if (lane == 0) wsum[wv] = acc;
    __syncthreads();
    if (tid == 0) {
        float bs = (wsum[0] + wsum[1] + wsum[2] + wsum[3]) * lscale;
        __hip_atomic_store(&partials[i], bs, __ATOMIC_RELEASE, __HIP_MEMORY_SCOPE_AGENT);
        ticket_s = __hip_atomic_fetch_add(counter, 1u, __ATOMIC_ACQ_REL,
                                          __HIP_MEMORY_SCOPE_AGENT);
    }
    __syncthreads();
    if (ticket_s == LOSS_BLOCKS - 1) {               // last block: finish
        float s = __hip_atomic_load(&partials[tid], __ATOMIC_RELAXED,
                                    __HIP_MEMORY_SCOPE_AGENT)
                + __hip_atomic_load(&partials[tid + 256], __ATOMIC_RELAXED,
                                    __HIP_MEMORY_SCOPE_AGENT);
#pragma unroll
        for (int off = 32; off > 0; off >>= 1) s += __shfl_xor(s, off, 64);
        __syncthreads();
        if (lane == 0) wsum[wv] = s;
        __syncthreads();
        if (tid == 0) out[0] = wsum[0] + wsum[1] + wsum[2] + wsum[3];
    }
}

// ---------------------------------------------------------------- launch -----
extern "C" void kernel_launch(void* const* d_in, const int* in_sizes, int n_in,
                              void* d_out, int out_size, void* d_ws, size_t ws_size,
                              hipStream_t stream) {
    const float* x      = (const float*)d_in[0];   // 2097152 fp32
    const float* target = (const float*)d_in[1];   // 33554432 fp32
    float* out = (float*)d_out;

    __hip_bfloat16* feats = (__hip_bfloat16*)d_ws;                        // 4 MB
    float* g_part   = (float*)((char*)d_ws + FEATS_ELEMS * sizeof(__hip_bfloat16)); // 8 MB
    float* g_pad    = g_part + SPLITK * CH * CH;                          // 1.5 MB
    float* partials = g_pad + CH * GPAD;                                  // 2 KB
    unsigned int* counter = (unsigned int*)(partials + LOSS_BLOCKS);

    convert_kernel<<<FEATS_ELEMS / (256 * 8), 256, 0, stream>>>(x, feats);
    gemm_kernel<<<dim3(CH / BM, CH / BM, SPLITK), 256, 0, stream>>>(feats, g_part);
    reduce_pad_kernel<<<CH * CH / 4 / 256, 256, 0, stream>>>(g_part, g_pad, counter);
    loss_kernel<<<LOSS_BLOCKS, 256, 0, stream>>>(target, g_pad, partials, counter, out);
}

// Round 3
// 216.008 us; speedup vs baseline: 1.1486x; 1.1486x over previous
//
#include <hip/hip_runtime.h>
#include <hip/hip_bf16.h>

// StyleLoss — x (1,512,64,64) fp32, target (512,256,256) fp32 -> scalar loss.
// loss = mean_{i,a,b}( (g_full[(i+a)%512,(i+b)%512]/2^20 - target[i,a,b])^2 ) * 1e6
// g_full = feats @ feats^T, feats = x reshaped (512, 4096), bf16 MFMA (tol ~2%).
//
// R6: REVERT of R5 (512-block loss was latency-bound: 94us @ 9.6% HBM, occ 17%;
// 2048 blocks = the TLP that hides load latency). Back to the measured-208.8
// R4 structure. ONE new lever: gemm dispatch carries 256 extra prefetch blocks
// (grid.z 4->8) that stream the first 33.5 MB of target into L3 during gemm's
// compute shadow (HBM idle there; feats is L2/L3-resident). Loss then serves
// that slice from L3.
//
// ws: [0,4MB) bf16 feats; [4,8MB) fp32 g_part[4][512*512];
//     [8MB,+1.5MB) fp32 g_pad[512][768]; then fp32 partials[2048].

typedef __attribute__((ext_vector_type(8))) short bf16x8;   // 8 bf16 in 4 VGPRs
typedef __attribute__((ext_vector_type(4))) float f32x4;

#define CH 512
#define KDIM 4096
#define FEATS_ELEMS (CH * KDIM)
#define SPLITK 4
#define LOSS_BLOCKS 2048
#define GPAD 768
#define PF_Z 4            // extra grid.z slices of prefetch blocks (4*64 = 256)

// ---------------------------------------------------------------- convert ----
__global__ __launch_bounds__(256) void convert_kernel(const float* __restrict__ x,
                                                      __hip_bfloat16* __restrict__ feats) {
    int idx = blockIdx.x * 256 + threadIdx.x;   // 262144 threads, 8 elems each
    const float4* x4 = (const float4*)x;
    float4 v0 = x4[idx * 2 + 0];
    float4 v1 = x4[idx * 2 + 1];
    float f[8] = {v0.x, v0.y, v0.z, v0.w, v1.x, v1.y, v1.z, v1.w};
    union { ushort u[8]; uint4 v; } o;
#pragma unroll
    for (int i = 0; i < 8; ++i) {
        __hip_bfloat16 b = __float2bfloat16(f[i]);
        o.u[i] = *reinterpret_cast<ushort*>(&b);
    }
    *reinterpret_cast<uint4*>(feats + idx * 8) = o.v;
}

// ---------------------------------------------------------------- gemm -------
// C = F * F^T, F 512x4096 bf16 row-major. 64x64 tile, BK=64, split-K=4
// (256 gemm blocks), register prefetch, plain stores into slice g_part[kz].
// Blocks with kz >= SPLITK are TARGET-PREFETCH blocks: stream 128 KB each of
// target (keep-alive asm, no stores) to warm L3 while gemm computes.
#define BM 64
#define BK 64
#define LDT 72   // padded LDS stride in bf16: 144 B (b128-aligned, 2-way alias = free)

__global__ __launch_bounds__(256) void gemm_kernel(const __hip_bfloat16* __restrict__ feats,
                                                   float* __restrict__ g_part,
                                                   const float* __restrict__ target) {
    __shared__ __hip_bfloat16 a_tile[BM * LDT];
    __shared__ __hip_bfloat16 b_tile[BM * LDT];

    const int bm = blockIdx.x, bn = blockIdx.y, kz = blockIdx.z;
    const int tid  = threadIdx.x;

    if (kz >= SPLITK) {                              // ---- prefetch role ----
        const int pid = (kz - SPLITK) * 64 + bn * 8 + bm;       // 0..255
        const float4* t4 = (const float4*)target + (size_t)pid * 8192 + tid;
#pragma unroll 8
        for (int it = 0; it < 32; ++it) {            // 32 x 16B/thread = 128 KB/block
            float4 v = t4[it * 256];
            asm volatile("" :: "v"(v.x), "v"(v.y), "v"(v.z), "v"(v.w));
        }
        return;
    }

    const int lane = tid & 63;
    const int w    = tid >> 6;        // wave 0..3 -> M rows w*16..w*16+15
    const int m    = lane & 15;
    const int q    = lane >> 4;       // quad: k offset q*8

    const int srow = tid >> 3;        // staging row 0..31 (+32 for p=1)
    const int scol = (tid & 7) * 8;   // 0..56 step 8

    f32x4 acc[4] = {};                // 4 N-subtiles of 16 cols

    const int NT = (KDIM / SPLITK) / BK;            // 16 k-tiles per block
    const int k0base = kz * (KDIM / SPLITK);        // 1024 per split

    const __hip_bfloat16* arow0 = feats + (size_t)(bm * 64 + srow) * KDIM + k0base + scol;
    const __hip_bfloat16* brow0 = feats + (size_t)(bn * 64 + srow) * KDIM + k0base + scol;

    uint4 pa[2], pb[2];
#pragma unroll
    for (int p = 0; p < 2; ++p) {
        pa[p] = *(const uint4*)(arow0 + (size_t)p * 32 * KDIM);
        pb[p] = *(const uint4*)(brow0 + (size_t)p * 32 * KDIM);
    }

    for (int kt = 0; kt < NT; ++kt) {
        if (kt > 0) __syncthreads();               // previous MFMA reads done
#pragma unroll
        for (int p = 0; p < 2; ++p) {
            uint* ap = (uint*)(a_tile + (srow + p * 32) * LDT + scol);
            ap[0] = pa[p].x; ap[1] = pa[p].y; ap[2] = pa[p].z; ap[3] = pa[p].w;
            uint* bp = (uint*)(b_tile + (srow + p * 32) * LDT + scol);
            bp[0] = pb[p].x; bp[1] = pb[p].y; bp[2] = pb[p].z; bp[3] = pb[p].w;
        }
        __syncthreads();
        if (kt + 1 < NT) {                         // prefetch next tile (overlaps MFMA)
            const int ko = (kt + 1) * BK;
#pragma unroll
            for (int p = 0; p < 2; ++p) {
                pa[p] = *(const uint4*)(arow0 + (size_t)p * 32 * KDIM + ko);
                pb[p] = *(const uint4*)(brow0 + (size_t)p * 32 * KDIM + ko);
            }
        }
#pragma unroll
        for (int ks = 0; ks < 2; ++ks) {
            const int kk = ks * 32 + q * 8;
            bf16x8 afrag = *(const bf16x8*)(a_tile + (w * 16 + m) * LDT + kk);
#pragma unroll
            for (int j = 0; j < 4; ++j) {
                bf16x8 bfrag = *(const bf16x8*)(b_tile + (j * 16 + m) * LDT + kk);
                acc[j] = __builtin_amdgcn_mfma_f32_16x16x32_bf16(afrag, bfrag, acc[j], 0, 0, 0);
            }
        }
    }

    // Epilogue: C/D layout col = lane&15, row = (lane>>4)*4 + reg (verified m89/m91)
    float* gp = g_part + ((size_t)kz << 18);
    const int col = lane & 15;
    const int rq  = (lane >> 4) * 4;
#pragma unroll
    for (int j = 0; j < 4; ++j) {
#pragma unroll
        for (int reg = 0; reg < 4; ++reg) {
            const int rg = bm * 64 + w * 16 + rq + reg;
            const int cg = bn * 64 + j * 16 + col;
            gp[rg * CH + cg] = acc[j][reg];
        }
    }
}

// ---------------------------------------------------------------- reduce -----
// g_pad[row][0..767] = gscale * sum of 4 split-K slices; cols 512..767 duplicate
// cols 0..255 so the loss kernel can read (i+b)%512 as ONE contiguous float4.
__global__ __launch_bounds__(256) void reduce_pad_kernel(const float* __restrict__ g_part,
                                                         float* __restrict__ g_pad) {
    const float gscale = 1.0f / 1048576.0f;          // 1/(b*local_ch*w*h)
    int t = blockIdx.x * 256 + threadIdx.x;          // 0..65535
    const float4* p = (const float4*)g_part;
    float4 s = p[t];
#pragma unroll
    for (int sl = 1; sl < SPLITK; ++sl) {
        float4 v = p[t + sl * 65536];
        s.x += v.x; s.y += v.y; s.z += v.z; s.w += v.w;
    }
    s.x *= gscale; s.y *= gscale; s.z *= gscale; s.w *= gscale;
    const int row = t >> 7;                          // 128 float4 per row
    const int c4  = t & 127;
    float4* dst = (float4*)(g_pad + (size_t)row * GPAD);
    dst[c4] = s;
    if (c4 < 64) dst[c4 + 128] = s;                  // duplicate cols 0..255
}

// ---------------------------------------------------------------- loss -------
// Block partial -> plain store to partials[blk]. 2048 blocks, i = blk>>2.
// g-read is ONE 16B load per (j,k): g_pad[row*768 + i + 4*lane .. +3].
__global__ __launch_bounds__(256) void loss_kernel(const float* __restrict__ target,
                                                   const float* __restrict__ g_pad,
                                                   float* __restrict__ partials) {
    const float lscale = 1.0e6f / 33554432.0f;       // WEIGHT / count

    const int tid  = threadIdx.x;
    const int lane = tid & 63;
    const int wv   = tid >> 6;
    const int blk  = blockIdx.x;
    const int i    = blk >> 2;                       // 4 blocks per i

    const float4* t4 = (const float4*)target;
    const float* gbase = g_pad + i + 4 * lane;       // column start, per thread
    float acc = 0.0f;

#pragma unroll
    for (int j = 0; j < 4; ++j) {
        float4 tv[4];
        float4 gv[4];
#pragma unroll
        for (int k = 0; k < 4; ++k) {
            const int idx4 = blk * 4096 + j * 1024 + k * 256 + tid;
            tv[k] = t4[idx4];
            const int a   = (blk & 3) * 64 + j * 16 + k * 4 + wv;   // = (idx4>>6)&255
            const int row = (i + a) & 511;
            __builtin_memcpy(&gv[k], gbase + (size_t)row * GPAD, sizeof(float4));
        }
#pragma unroll
        for (int k = 0; k < 4; ++k) {
            float d0 = gv[k].x - tv[k].x;
            float d1 = gv[k].y - tv[k].y;
            float d2 = gv[k].z - tv[k].z;
            float d3 = gv[k].w - tv[k].w;
            acc += d0 * d0 + d1 * d1 + d2 * d2 + d3 * d3;
        }
    }

    // wave reduce, then cross-wave via LDS, ONE plain store per block (no atomics)
#pragma unroll
    for (int off = 32; off > 0; off >>= 1) acc += __shfl_xor(acc, off, 64);
    __shared__ float wsum[4];
    if (lane == 0) wsum[wv] = acc;
    __syncthreads();
    if (tid == 0)
        partials[blk] = (wsum[0] + wsum[1] + wsum[2] + wsum[3]) * lscale;
}

// ---------------------------------------------------------------- finish -----
// Sum 2048 partials in one block; plain store to out (no memset needed).
__global__ __launch_bounds__(256) void finish_kernel(const float* __restrict__ partials,
                                                     float* __restrict__ out) {
    const int tid  = threadIdx.x;
    const int lane = tid & 63;
    const int wv   = tid >> 6;
    const float4* p = (const float4*)partials;       // 512 float4
    float4 a = p[tid], b = p[tid + 256];
    float s = a.x + a.y + a.z + a.w + b.x + b.y + b.z + b.w;
#pragma unroll
    for (int off = 32; off > 0; off >>= 1) s += __shfl_xor(s, off, 64);
    __shared__ float wsum[4];
    if (lane == 0) wsum[wv] = s;
    __syncthreads();
    if (tid == 0) out[0] = wsum[0] + wsum[1] + wsum[2] + wsum[3];
}

// ---------------------------------------------------------------- launch -----
extern "C" void kernel_launch(void* const* d_in, const int* in_sizes, int n_in,
                              void* d_out, int out_size, void* d_ws, size_t ws_size,
                              hipStream_t stream) {
    const float* x      = (const float*)d_in[0];   // 2097152 fp32
    const float* target = (const float*)d_in[1];   // 33554432 fp32
    float* out = (float*)d_out;

    __hip_bfloat16* feats = (__hip_bfloat16*)d_ws;                        // 4 MB
    float* g_part   = (float*)((char*)d_ws + FEATS_ELEMS * sizeof(__hip_bfloat16)); // 4 MB
    float* g_pad    = g_part + SPLITK * CH * CH;                          // 1.5 MB
    float* partials = g_pad + CH * GPAD;                                  // 8 KB

    convert_kernel<<<FEATS_ELEMS / (256 * 8), 256, 0, stream>>>(x, feats);
    gemm_kernel<<<dim3(CH / BM, CH / BM, SPLITK + PF_Z), 256, 0, stream>>>(feats, g_part, target);
    reduce_pad_kernel<<<CH * CH / 4 / 256, 256, 0, stream>>>(g_part, g_pad);
    loss_kernel<<<LOSS_BLOCKS, 256, 0, stream>>>(target, g_pad, partials);
    finish_kernel<<<1, 256, 0, stream>>>(partials, out);
}

// Round 4
// 212.770 us; speedup vs baseline: 1.1661x; 1.0152x over previous
//
#include <hip/hip_runtime.h>
#include <hip/hip_bf16.h>

// StyleLoss — x (1,512,64,64) fp32, target (512,256,256) fp32 -> scalar loss.
// loss = mean_{i,a,b}( (g_full[(i+a)%512,(i+b)%512]/2^20 - target[i,a,b])^2 ) * 1e6
// g_full = feats @ feats^T, feats = x reshaped (512, 4096), bf16 MFMA (tol ~2%).
//
// R7: revert R6's prefetch (+7us). Structure = measured-208.8 R4, minus the
// convert kernel: gemm reads x (fp32) directly and converts tiles to bf16
// during LDS staging (no cross-block dep, x is L2-resident after first touch).
// 5 -> 4 dispatches/iter: saves convert exec (~2.5us) + a launch gap (~1.5us)
// + 8 MB HBM traffic, costs ~+1us of cvt VALU inside gemm.
//
// Iteration anatomy (dispatch-ID GCD analysis): 4 harness poison fills ~157us
// (uncontrollable) + our kernels ~35us + gaps ~12us.
//
// ws: [0,4MB) fp32 g_part[4][512*512]; [4MB,+1.5MB) fp32 g_pad[512][768];
//     then fp32 partials[2048].

typedef __attribute__((ext_vector_type(8))) short bf16x8;   // 8 bf16 in 4 VGPRs
typedef __attribute__((ext_vector_type(4))) float f32x4;

#define CH 512
#define KDIM 4096
#define SPLITK 4
#define LOSS_BLOCKS 2048
#define GPAD 768

// ---------------------------------------------------------------- gemm -------
// C = F * F^T, F = x viewed as 512x4096 fp32, converted to bf16 on the fly.
// 64x64 tile, BK=64, split-K=4 (256 blocks), register prefetch, plain stores
// into private slice g_part[kz].
#define BM 64
#define BK 64
#define LDT 72   // padded LDS stride in bf16: 144 B (b128-aligned, 2-way alias = free)

static __device__ inline uint4 cvt8_bf16(float4 a, float4 b) {
    float f[8] = {a.x, a.y, a.z, a.w, b.x, b.y, b.z, b.w};
    union { ushort u[8]; uint4 v; } o;
#pragma unroll
    for (int i = 0; i < 8; ++i) {
        __hip_bfloat16 h = __float2bfloat16(f[i]);
        o.u[i] = *reinterpret_cast<ushort*>(&h);
    }
    return o.v;
}

__global__ __launch_bounds__(256) void gemm_kernel(const float* __restrict__ x,
                                                   float* __restrict__ g_part) {
    __shared__ __hip_bfloat16 a_tile[BM * LDT];
    __shared__ __hip_bfloat16 b_tile[BM * LDT];

    const int bm = blockIdx.x, bn = blockIdx.y, kz = blockIdx.z;
    const int tid  = threadIdx.x;
    const int lane = tid & 63;
    const int w    = tid >> 6;        // wave 0..3 -> M rows w*16..w*16+15
    const int m    = lane & 15;
    const int q    = lane >> 4;       // quad: k offset q*8

    const int srow = tid >> 3;        // staging row 0..31 (+32 for p=1)
    const int scol = (tid & 7) * 8;   // 0..56 step 8

    f32x4 acc[4] = {};                // 4 N-subtiles of 16 cols

    const int NT = (KDIM / SPLITK) / BK;            // 16 k-tiles per block
    const int k0base = kz * (KDIM / SPLITK);        // 1024 per split

    const float* arow0 = x + (size_t)(bm * 64 + srow) * KDIM + k0base + scol;
    const float* brow0 = x + (size_t)(bn * 64 + srow) * KDIM + k0base + scol;

    float4 pa[2][2], pb[2][2];        // 8 floats per tile-row per p
#pragma unroll
    for (int p = 0; p < 2; ++p) {
        const float* ap = arow0 + (size_t)p * 32 * KDIM;
        const float* bp = brow0 + (size_t)p * 32 * KDIM;
        pa[p][0] = *(const float4*)(ap);     pa[p][1] = *(const float4*)(ap + 4);
        pb[p][0] = *(const float4*)(bp);     pb[p][1] = *(const float4*)(bp + 4);
    }

    for (int kt = 0; kt < NT; ++kt) {
        if (kt > 0) __syncthreads();               // previous MFMA reads done
#pragma unroll
        for (int p = 0; p < 2; ++p) {
            uint4 av = cvt8_bf16(pa[p][0], pa[p][1]);
            uint4 bv = cvt8_bf16(pb[p][0], pb[p][1]);
            uint* ap = (uint*)(a_tile + (srow + p * 32) * LDT + scol);
            ap[0] = av.x; ap[1] = av.y; ap[2] = av.z; ap[3] = av.w;
            uint* bp = (uint*)(b_tile + (srow + p * 32) * LDT + scol);
            bp[0] = bv.x; bp[1] = bv.y; bp[2] = bv.z; bp[3] = bv.w;
        }
        __syncthreads();
        if (kt + 1 < NT) {                         // prefetch next tile (overlaps MFMA)
            const int ko = (kt + 1) * BK;
#pragma unroll
            for (int p = 0; p < 2; ++p) {
                const float* ap = arow0 + (size_t)p * 32 * KDIM + ko;
                const float* bp = brow0 + (size_t)p * 32 * KDIM + ko;
                pa[p][0] = *(const float4*)(ap);     pa[p][1] = *(const float4*)(ap + 4);
                pb[p][0] = *(const float4*)(bp);     pb[p][1] = *(const float4*)(bp + 4);
            }
        }
#pragma unroll
        for (int ks = 0; ks < 2; ++ks) {
            const int kk = ks * 32 + q * 8;
            bf16x8 afrag = *(const bf16x8*)(a_tile + (w * 16 + m) * LDT + kk);
#pragma unroll
            for (int j = 0; j < 4; ++j) {
                bf16x8 bfrag = *(const bf16x8*)(b_tile + (j * 16 + m) * LDT + kk);
                acc[j] = __builtin_amdgcn_mfma_f32_16x16x32_bf16(afrag, bfrag, acc[j], 0, 0, 0);
            }
        }
    }

    // Epilogue: C/D layout col = lane&15, row = (lane>>4)*4 + reg (verified m89/m91)
    float* gp = g_part + ((size_t)kz << 18);
    const int col = lane & 15;
    const int rq  = (lane >> 4) * 4;
#pragma unroll
    for (int j = 0; j < 4; ++j) {
#pragma unroll
        for (int reg = 0; reg < 4; ++reg) {
            const int rg = bm * 64 + w * 16 + rq + reg;
            const int cg = bn * 64 + j * 16 + col;
            gp[rg * CH + cg] = acc[j][reg];
        }
    }
}

// ---------------------------------------------------------------- reduce -----
// g_pad[row][0..767] = gscale * sum of 4 split-K slices; cols 512..767 duplicate
// cols 0..255 so the loss kernel can read (i+b)%512 as ONE contiguous float4.
__global__ __launch_bounds__(256) void reduce_pad_kernel(const float* __restrict__ g_part,
                                                         float* __restrict__ g_pad) {
    const float gscale = 1.0f / 1048576.0f;          // 1/(b*local_ch*w*h)
    int t = blockIdx.x * 256 + threadIdx.x;          // 0..65535
    const float4* p = (const float4*)g_part;
    float4 s = p[t];
#pragma unroll
    for (int sl = 1; sl < SPLITK; ++sl) {
        float4 v = p[t + sl * 65536];
        s.x += v.x; s.y += v.y; s.z += v.z; s.w += v.w;
    }
    s.x *= gscale; s.y *= gscale; s.z *= gscale; s.w *= gscale;
    const int row = t >> 7;                          // 128 float4 per row
    const int c4  = t & 127;
    float4* dst = (float4*)(g_pad + (size_t)row * GPAD);
    dst[c4] = s;
    if (c4 < 64) dst[c4 + 128] = s;                  // duplicate cols 0..255
}

// ---------------------------------------------------------------- loss -------
// Block partial -> plain store to partials[blk]. 2048 blocks, i = blk>>2.
// g-read is ONE 16B load per (j,k): g_pad[row*768 + i + 4*lane .. +3].
__global__ __launch_bounds__(256) void loss_kernel(const float* __restrict__ target,
                                                   const float* __restrict__ g_pad,
                                                   float* __restrict__ partials) {
    const float lscale = 1.0e6f / 33554432.0f;       // WEIGHT / count

    const int tid  = threadIdx.x;
    const int lane = tid & 63;
    const int wv   = tid >> 6;
    const int blk  = blockIdx.x;
    const int i    = blk >> 2;                       // 4 blocks per i

    const float4* t4 = (const float4*)target;
    const float* gbase = g_pad + i + 4 * lane;       // column start, per thread
    float acc = 0.0f;

#pragma unroll
    for (int j = 0; j < 4; ++j) {
        float4 tv[4];
        float4 gv[4];
#pragma unroll
        for (int k = 0; k < 4; ++k) {
            const int idx4 = blk * 4096 + j * 1024 + k * 256 + tid;
            tv[k] = t4[idx4];
            const int a   = (blk & 3) * 64 + j * 16 + k * 4 + wv;   // = (idx4>>6)&255
            const int row = (i + a) & 511;
            __builtin_memcpy(&gv[k], gbase + (size_t)row * GPAD, sizeof(float4));
        }
#pragma unroll
        for (int k = 0; k < 4; ++k) {
            float d0 = gv[k].x - tv[k].x;
            float d1 = gv[k].y - tv[k].y;
            float d2 = gv[k].z - tv[k].z;
            float d3 = gv[k].w - tv[k].w;
            acc += d0 * d0 + d1 * d1 + d2 * d2 + d3 * d3;
        }
    }

    // wave reduce, then cross-wave via LDS, ONE plain store per block (no atomics)
#pragma unroll
    for (int off = 32; off > 0; off >>= 1) acc += __shfl_xor(acc, off, 64);
    __shared__ float wsum[4];
    if (lane == 0) wsum[wv] = acc;
    __syncthreads();
    if (tid == 0)
        partials[blk] = (wsum[0] + wsum[1] + wsum[2] + wsum[3]) * lscale;
}

// ---------------------------------------------------------------- finish -----
// Sum 2048 partials in one block; plain store to out (no memset needed).
__global__ __launch_bounds__(256) void finish_kernel(const float* __restrict__ partials,
                                                     float* __restrict__ out) {
    const int tid  = threadIdx.x;
    const int lane = tid & 63;
    const int wv   = tid >> 6;
    const float4* p = (const float4*)partials;       // 512 float4
    float4 a = p[tid], b = p[tid + 256];
    float s = a.x + a.y + a.z + a.w + b.x + b.y + b.z + b.w;
#pragma unroll
    for (int off = 32; off > 0; off >>= 1) s += __shfl_xor(s, off, 64);
    __shared__ float wsum[4];
    if (lane == 0) wsum[wv] = s;
    __syncthreads();
    if (tid == 0) out[0] = wsum[0] + wsum[1] + wsum[2] + wsum[3];
}

// ---------------------------------------------------------------- launch -----
extern "C" void kernel_launch(void* const* d_in, const int* in_sizes, int n_in,
                              void* d_out, int out_size, void* d_ws, size_t ws_size,
                              hipStream_t stream) {
    const float* x      = (const float*)d_in[0];   // 2097152 fp32
    const float* target = (const float*)d_in[1];   // 33554432 fp32
    float* out = (float*)d_out;

    float* g_part   = (float*)d_ws;                                       // 4 MB
    float* g_pad    = g_part + SPLITK * CH * CH;                          // 1.5 MB
    float* partials = g_pad + CH * GPAD;                                  // 8 KB

    gemm_kernel<<<dim3(CH / BM, CH / BM, SPLITK), 256, 0, stream>>>(x, g_part);
    reduce_pad_kernel<<<CH * CH / 4 / 256, 256, 0, stream>>>(g_part, g_pad);
    loss_kernel<<<LOSS_BLOCKS, 256, 0, stream>>>(target, g_pad, partials);
    finish_kernel<<<1, 256, 0, stream>>>(partials, out);
}

// Round 5
// 210.889 us; speedup vs baseline: 1.1765x; 1.0089x over previous
//
#include <hip/hip_runtime.h>
#include <hip/hip_bf16.h>

// StyleLoss — x (1,512,64,64) fp32, target (512,256,256) fp32 -> scalar loss.
// loss = mean_{i,a,b}( (g_full[(i+a)%512,(i+b)%512]/2^20 - target[i,a,b])^2 ) * 1e6
//
// R8: algebraic restructure.  Sum(g~-t)^2 = Sum_rc n*g~^2 - 2*Sum_rc g~*S1 + Sum t^2
//   with S1[r,c] = sum over the orbit {(i,a,b): (i+a)%512==r,(i+b)%512==c} of t,
//   and n(r,c) = 256 - min((r-c)%512,(c-r)%512) (closed form).
// S1 and Sum t^2 are independent of g => the 134 MB target pass runs CONCURRENTLY
// with the gemm in one block-specialized kernel (roles independent, no sync):
//   blocks [0,256):  gemm C=F*F^T (bf16 MFMA, split-K=4, inline fp32->bf16 cvt)
//   blocks [256,768): S1 rows: r = bid-256; 256 x 1KB coalesced segments,
//                     per-wave LDS stage + REGISTER accumulation (lane owns
//                     cols c == lane mod 64; LDS gather is 2-way bank = free).
// Then final_partial (256 blocks): g~ = sum(g_part)/2^20, acc n*g~^2 - 2*g~*S1;
// finish (1 block): + Sum t^2, scale. 5 -> 3 dispatches; target stream hidden.
//
// ws: [0,4MB) fp32 g_part[4][512*512]; [4,5MB) fp32 S1[512][512];
//     fp32 t2part[512]; fp32 partial2[256].

typedef __attribute__((ext_vector_type(8))) short bf16x8;   // 8 bf16 in 4 VGPRs
typedef __attribute__((ext_vector_type(4))) float f32x4;

#define CH 512
#define KDIM 4096
#define SPLITK 4

#define BM 64
#define BK 64
#define LDT 72   // padded LDS stride in bf16: 144 B (b128-aligned, 2-way alias = free)

static __device__ inline uint4 cvt8_bf16(float4 a, float4 b) {
    float f[8] = {a.x, a.y, a.z, a.w, b.x, b.y, b.z, b.w};
    union { ushort u[8]; uint4 v; } o;
#pragma unroll
    for (int i = 0; i < 8; ++i) {
        __hip_bfloat16 h = __float2bfloat16(f[i]);
        o.u[i] = *reinterpret_cast<ushort*>(&h);
    }
    return o.v;
}

// ---------------------------------------------------------------- fused ------
__global__ __launch_bounds__(256) void fused_main_kernel(const float* __restrict__ x,
                                                         const float* __restrict__ target,
                                                         float* __restrict__ g_part,
                                                         float* __restrict__ S1g,
                                                         float* __restrict__ t2part) {
    __shared__ __hip_bfloat16 a_tile[BM * LDT];
    __shared__ __hip_bfloat16 b_tile[BM * LDT];
    __shared__ float wavebuf[4][2][256];   // per-wave double-buffered segment stage
    __shared__ float comb[4][512];         // cross-wave S1 combine
    __shared__ float t2w[4];

    const int bid = blockIdx.x;
    const int tid = threadIdx.x;
    const int lane = tid & 63;
    const int w    = tid >> 6;

    if (bid < 256) {
        // ======================== GEMM role (R7 kernel, verified) ========================
        const int bm = bid & 7, bn = (bid >> 3) & 7, kz = bid >> 6;
        const int m    = lane & 15;
        const int q    = lane >> 4;       // quad: k offset q*8
        const int srow = tid >> 3;        // staging row 0..31 (+32 for p=1)
        const int scol = (tid & 7) * 8;   // 0..56 step 8

        f32x4 acc[4] = {};

        const int NT = (KDIM / SPLITK) / BK;            // 16 k-tiles per block
        const int k0base = kz * (KDIM / SPLITK);        // 1024 per split

        const float* arow0 = x + (size_t)(bm * 64 + srow) * KDIM + k0base + scol;
        const float* brow0 = x + (size_t)(bn * 64 + srow) * KDIM + k0base + scol;

        float4 pa[2][2], pb[2][2];
#pragma unroll
        for (int p = 0; p < 2; ++p) {
            const float* ap = arow0 + (size_t)p * 32 * KDIM;
            const float* bp = brow0 + (size_t)p * 32 * KDIM;
            pa[p][0] = *(const float4*)(ap);  pa[p][1] = *(const float4*)(ap + 4);
            pb[p][0] = *(const float4*)(bp);  pb[p][1] = *(const float4*)(bp + 4);
        }

        for (int kt = 0; kt < NT; ++kt) {
            if (kt > 0) __syncthreads();
#pragma unroll
            for (int p = 0; p < 2; ++p) {
                uint4 av = cvt8_bf16(pa[p][0], pa[p][1]);
                uint4 bv = cvt8_bf16(pb[p][0], pb[p][1]);
                uint* ap = (uint*)(a_tile + (srow + p * 32) * LDT + scol);
                ap[0] = av.x; ap[1] = av.y; ap[2] = av.z; ap[3] = av.w;
                uint* bp = (uint*)(b_tile + (srow + p * 32) * LDT + scol);
                bp[0] = bv.x; bp[1] = bv.y; bp[2] = bv.z; bp[3] = bv.w;
            }
            __syncthreads();
            if (kt + 1 < NT) {
                const int ko = (kt + 1) * BK;
#pragma unroll
                for (int p = 0; p < 2; ++p) {
                    const float* ap = arow0 + (size_t)p * 32 * KDIM + ko;
                    const float* bp = brow0 + (size_t)p * 32 * KDIM + ko;
                    pa[p][0] = *(const float4*)(ap);  pa[p][1] = *(const float4*)(ap + 4);
                    pb[p][0] = *(const float4*)(bp);  pb[p][1] = *(const float4*)(bp + 4);
                }
            }
#pragma unroll
            for (int ks = 0; ks < 2; ++ks) {
                const int kk = ks * 32 + q * 8;
                bf16x8 afrag = *(const bf16x8*)(a_tile + (w * 16 + m) * LDT + kk);
#pragma unroll
                for (int j = 0; j < 4; ++j) {
                    bf16x8 bfrag = *(const bf16x8*)(b_tile + (j * 16 + m) * LDT + kk);
                    acc[j] = __builtin_amdgcn_mfma_f32_16x16x32_bf16(afrag, bfrag, acc[j], 0, 0, 0);
                }
            }
        }

        // C/D layout: col = lane&15, row = (lane>>4)*4 + reg (verified m89/m91)
        float* gp = g_part + ((size_t)kz << 18);
        const int col = lane & 15;
        const int rq  = (lane >> 4) * 4;
#pragma unroll
        for (int j = 0; j < 4; ++j) {
#pragma unroll
            for (int reg = 0; reg < 4; ++reg) {
                const int rg = bm * 64 + w * 16 + rq + reg;
                const int cg = bn * 64 + j * 16 + col;
                gp[rg * CH + cg] = acc[j][reg];
            }
        }
        return;
    }

    // ======================== S1 role: one output row r per block ========================
    // Row r sums 256 segments t[i, a, 0..255] with i=(r-a)&511, shifted to cols (i+b)&511.
    // Wave w handles a = 64w..64w+63.  Lane owns cols c = lane+64k (k=0..7) in registers.
    const int r = bid - 256;                          // 0..511
    const float4* t4 = (const float4*)target;

    float accv[8] = {};
    float t2 = 0.0f;

    auto segload = [&](int s) -> float4 {
        const int a = w * 64 + s;
        const int i = (r - a) & 511;
        return t4[i * 16384 + a * 64 + lane];         // 1KB segment, coalesced
    };
    auto process = [&](float4 v, int s, int p) {
        const int a = w * 64 + s;
        const int i = (r - a) & 511;
        t2 += v.x * v.x + v.y * v.y + v.z * v.z + v.w * v.w;
        *(float4*)&wavebuf[w][p][lane * 4] = v;       // wave-private stage (in-order DS pipe)
#pragma unroll
        for (int k = 0; k < 8; ++k) {
            const int b = (lane + 64 * k - i) & 511;  // source pos; valid if <256
            if (b < 256) accv[k] += wavebuf[w][p][b]; // bank (lane-i)%32: 2-way = free
        }
    };

    float4 va = segload(0), vb = segload(1);
    for (int s = 0; s < 64; s += 2) {                 // 2-deep prefetch pipeline
        float4 vn0 = {}, vn1 = {};
        if (s + 2 < 64) { vn0 = segload(s + 2); vn1 = segload(s + 3); }
        process(va, s, 0);
        process(vb, s + 1, 1);
        va = vn0; vb = vn1;
    }

    // combine waves: comb[w][c], then 256 threads write S1 row (2 cols each)
#pragma unroll
    for (int k = 0; k < 8; ++k) comb[w][lane + 64 * k] = accv[k];
#pragma unroll
    for (int off = 32; off > 0; off >>= 1) t2 += __shfl_xor(t2, off, 64);
    if (lane == 0) t2w[w] = t2;
    __syncthreads();
    const float s0 = comb[0][tid]       + comb[1][tid]       + comb[2][tid]       + comb[3][tid];
    const float s1 = comb[0][tid + 256] + comb[1][tid + 256] + comb[2][tid + 256] + comb[3][tid + 256];
    S1g[r * CH + tid]       = s0;
    S1g[r * CH + tid + 256] = s1;
    if (tid == 0) t2part[r] = t2w[0] + t2w[1] + t2w[2] + t2w[3];
}

// ---------------------------------------------------------------- final ------
// 256 blocks x 256 threads, 4 cells/thread: g~ = sum_k g_part / 2^20;
// acc += n(r,c)*g~^2 - 2*g~*S1.   n = 256 - min((r-c)&511,(c-r)&511).
__global__ __launch_bounds__(256) void final_partial_kernel(const float* __restrict__ g_part,
                                                            const float* __restrict__ S1g,
                                                            float* __restrict__ partial2) {
    const float gscale = 1.0f / 1048576.0f;
    const int tid = threadIdx.x, bid = blockIdx.x;
    const int lane = tid & 63, wv = tid >> 6;
    const int cell = (bid * 256 + tid) * 4;          // linear rc, row-aligned (512%4==0)
    const int r = cell >> 9, c0 = cell & 511;

    float4 g = *(const float4*)(g_part + cell);
#pragma unroll
    for (int sl = 1; sl < SPLITK; ++sl) {
        float4 v = *(const float4*)(g_part + sl * (CH * CH) + cell);
        g.x += v.x; g.y += v.y; g.z += v.z; g.w += v.w;
    }
    float4 s1 = *(const float4*)(S1g + cell);

    float gg[4] = {g.x, g.y, g.z, g.w};
    float ss[4] = {s1.x, s1.y, s1.z, s1.w};
    float acc = 0.0f;
#pragma unroll
    for (int j = 0; j < 4; ++j) {
        const int c  = c0 + j;
        const int d1 = (r - c) & 511;
        const int d2 = (c - r) & 511;
        const float n = (float)(256 - (d1 < d2 ? d1 : d2));
        const float gt = gg[j] * gscale;
        acc += n * gt * gt - 2.0f * gt * ss[j];
    }

#pragma unroll
    for (int off = 32; off > 0; off >>= 1) acc += __shfl_xor(acc, off, 64);
    __shared__ float wsum[4];
    if (lane == 0) wsum[wv] = acc;
    __syncthreads();
    if (tid == 0) partial2[bid] = wsum[0] + wsum[1] + wsum[2] + wsum[3];
}

// ---------------------------------------------------------------- finish -----
// out = (sum partial2[256] + sum t2part[512]) * WEIGHT/count
__global__ __launch_bounds__(256) void finish_kernel(const float* __restrict__ partial2,
                                                     const float* __restrict__ t2part,
                                                     float* __restrict__ out) {
    const float lscale = 1.0e6f / 33554432.0f;
    const int tid  = threadIdx.x;
    const int lane = tid & 63;
    const int wv   = tid >> 6;
    float s = partial2[tid] + t2part[tid] + t2part[tid + 256];
#pragma unroll
    for (int off = 32; off > 0; off >>= 1) s += __shfl_xor(s, off, 64);
    __shared__ float wsum[4];
    if (lane == 0) wsum[wv] = s;
    __syncthreads();
    if (tid == 0) out[0] = (wsum[0] + wsum[1] + wsum[2] + wsum[3]) * lscale;
}

// ---------------------------------------------------------------- launch -----
extern "C" void kernel_launch(void* const* d_in, const int* in_sizes, int n_in,
                              void* d_out, int out_size, void* d_ws, size_t ws_size,
                              hipStream_t stream) {
    const float* x      = (const float*)d_in[0];   // 2097152 fp32
    const float* target = (const float*)d_in[1];   // 33554432 fp32
    float* out = (float*)d_out;

    float* g_part   = (float*)d_ws;                     // 4 MB  [4][512*512]
    float* S1g      = g_part + SPLITK * CH * CH;        // 1 MB  [512][512]
    float* t2part   = S1g + CH * CH;                    // 2 KB
    float* partial2 = t2part + CH;                      // 1 KB

    fused_main_kernel<<<768, 256, 0, stream>>>(x, target, g_part, S1g, t2part);
    final_partial_kernel<<<256, 256, 0, stream>>>(g_part, S1g, partial2);
    finish_kernel<<<1, 256, 0, stream>>>(partial2, t2part, out);
}